// Round 14
// baseline (823.905 us; speedup 1.0000x reference)
//
#include <hip/hip_runtime.h>
#include <hip/hip_bf16.h>
#include <math.h>

typedef short short8 __attribute__((ext_vector_type(8)));
typedef short short4v __attribute__((ext_vector_type(4)));
typedef float f32x4 __attribute__((ext_vector_type(4)));

#define NCC  32768
#define G    4

// swizzled-weight region offsets in d_ws (units: unsigned short)
#define G1_OFF 0        // in_proj  768x256
#define G2_OFF 196608   // out_proj 256x256
#define G3_OFF 262144   // ff1      512x256
#define G4_OFF 393216   // ff2      256x512
#define O1_OFF 524288   // o1 (first 256 of K=257) 512x256
#define O2_OFF 655360   // o2       256x512
#define SWZ_SHORTS 786432
#define W256_BYTE_OFF (SWZ_SHORTS * 2)
#define FLAG_BYTE_OFF (W256_BYTE_OFF + 2048)

// padded LDS strides (f32) for pool buffers
#define PX2_ST 260
#define PGF_ST 520

__device__ __forceinline__ float gelu_f(float x) {
    return x * 0.5f * (1.0f + erff(x * 0.70710678118654752f));
}
__device__ __forceinline__ unsigned short f2bf(float f) {
    __hip_bfloat16 h = __float2bfloat16(f);
    return *reinterpret_cast<unsigned short*>(&h);
}
__device__ __forceinline__ int aswz(int row, int scol) {
    return row * 256 + (scol ^ ((row & 7) << 3));
}
__device__ __forceinline__ int qswz(int row, int scol) {
    return row * 512 + (scol ^ ((row & 7) << 3));
}
__device__ __forceinline__ int vtswz(int d, int j) {
    return d * 32 + (j ^ ((d & 7) << 2));
}

template<int KTS>
__device__ __forceinline__ void load_bgrp(short8 (&b)[KTS], const unsigned short* __restrict__ base) {
    #pragma unroll
    for (int kt = 0; kt < KTS; kt++)
        b[kt] = *reinterpret_cast<const short8*>(base + (size_t)kt * 512);
}

// ---- one-time weight swizzle into MFMA B-fragment order ----
__global__ void conv_weights(const float* __restrict__ w1, const float* __restrict__ w2,
                             const float* __restrict__ w3, const float* __restrict__ w4,
                             const float* __restrict__ o1, const float* __restrict__ o2,
                             unsigned short* __restrict__ dst, float* __restrict__ w256) {
    int i = blockIdx.x * 256 + threadIdx.x;
    if (i < 98304) {
        const float* src; int kts, sk, base;
        if (i < 24576)      { src = w1; kts = 8;  sk = 256; base = 0; }
        else if (i < 32768) { src = w2; kts = 8;  sk = 256; base = 24576; }
        else if (i < 49152) { src = w3; kts = 8;  sk = 256; base = 32768; }
        else if (i < 65536) { src = w4; kts = 16; sk = 512; base = 49152; }
        else if (i < 81920) { src = o1; kts = 8;  sk = 257; base = 65536; }
        else                { src = o2; kts = 16; sk = 512; base = 81920; }
        int li   = i - base;
        int lane = li & 63;
        int fi   = li >> 6;
        int kt   = fi % kts;
        int nt   = fi / kts;
        int col  = nt * 16 + (lane & 15);
        int k    = kt * 32 + (lane >> 4) * 8;
        const float* s = src + (size_t)col * sk + k;
        unsigned short* d = dst + (size_t)i * 8;
        #pragma unroll
        for (int e = 0; e < 8; e++) d[e] = f2bf(s[e]);
    } else if (i < 98816) {
        int c = i - 98304;
        w256[c] = o1[(size_t)c * 257 + 256];
    }
}

// ---- mask storage format detect: 0=int32, 1=byte, 2=float32 ----
__global__ void detect_mask_fmt(const unsigned int* __restrict__ mw, int nwords, int* __restrict__ flag) {
    __shared__ int s_bad_int, s_bad_float;
    if (threadIdx.x == 0) { s_bad_int = 0; s_bad_float = 0; }
    __syncthreads();
    int bad_int = 0, bad_float = 0;
    for (int i = threadIdx.x; i < nwords; i += blockDim.x) {
        unsigned int w = mw[i];
        if (w > 1u) bad_int = 1;
        if (w != 0u && w != 0x3F800000u) bad_float = 1;
    }
    if (bad_int)   atomicOr(&s_bad_int, 1);
    if (bad_float) atomicOr(&s_bad_float, 1);
    __syncthreads();
    if (threadIdx.x == 0)
        *flag = (!s_bad_int) ? 0 : ((!s_bad_float) ? 2 : 1);
}

// ===================== main transformer kernel =====================
// 512 threads (8 waves), G=4. Per-wave tile: 1 M-tile (16 rows) x 64 cols.
// Live set ~100 regs; bare launch_bounds(512) -> compiler targets 128 (R8
// precedent) -> no spill; runtime occupancy 4 waves/SIMD (VGPR-limited).
__global__ __launch_bounds__(512)
void tsa_main(const float* __restrict__ v,
              const int* __restrict__ batch_idx,
              const void* __restrict__ mask,
              const float* __restrict__ pos_embed,
              const float* __restrict__ ln1_w, const float* __restrict__ ln1_b,
              const float* __restrict__ in_proj_b,
              const float* __restrict__ out_proj_b,
              const float* __restrict__ ln2_w, const float* __restrict__ ln2_b,
              const float* __restrict__ ff1_b, const float* __restrict__ ff2_b,
              const unsigned short* __restrict__ wb,
              const int* __restrict__ mask_flag,
              float* __restrict__ out)
{
    __shared__ unsigned short qkbuf[32 * 512];      // lnred | Q|K -> ao | px2 | pgff
    __shared__ unsigned short abuf[32 * 256];       // LN1(swz) -> Vt(swz) -> LN2(swz)
    __shared__ unsigned short attw_s[2][4][16][16]; // P (bf16)
    __shared__ int s_idx[G][8];
    __shared__ int s_m[G];
    __shared__ int s_bi[G];

    float* lnred = reinterpret_cast<float*>(qkbuf);           // bytes 0..2048
    float* px2   = reinterpret_cast<float*>(qkbuf + 2048);    // bytes 4096..8256
    float* pgff  = reinterpret_cast<float*>(qkbuf + 8192);    // bytes 16384..24704

    const int tid  = threadIdx.x;
    const int lane = tid & 63;
    const int wid  = tid >> 6;       // 0..7
    const int cw   = wid & 3;        // N-quarter: cols cw*64..
    const int mg   = wid >> 2;       // M-half: rows mg*16..
    const int mrow0 = mg * 16;
    const int cq   = lane >> 4;
    const int cc   = lane & 15;
    const int cg0  = blockIdx.x * G;

    f32x4 xr[4];   // residual: row = mrow0+cq*4+r, col = cw*64+nt*16+cc

    // ---- mask parse (waves 0..3 -> chunk wid) ----
    if (wid < G) {
        int mf = *mask_flag;
        size_t base = (size_t)(cg0 + wid) * 64 + lane;
        int bit;
        if (mf == 0)      bit = ((const int*)mask)[base] != 0;
        else if (mf == 2) bit = ((const float*)mask)[base] != 0.0f;
        else              bit = ((const unsigned char*)mask)[base] != 0;
        unsigned long long bal = __ballot(bit);
        if (lane == 0) {
            int mm = 0; unsigned long long b = bal;
            while (b && mm < 8) { s_idx[wid][mm++] = __ffsll(b) - 1; b &= (b - 1); }
            for (int t = mm; t < 8; t++) s_idx[wid][t] = 0;
            s_m[wid]  = mm;
            s_bi[wid] = batch_idx[cg0 + wid];
        }
    }
    __syncthreads();

    // ---- gather helper: v+pos -> xr regs (16 rows x 64 cols per wave) ----
    auto do_gather = [&]() {
        int c  = mg * 2 + (cq >> 1);
        int m  = s_m[c];
        int bi = s_bi[c];
        #pragma unroll
        for (int rr = 0; rr < 4; rr++) {
            int rowin = (cq & 1) * 4 + rr;
            int vidx  = s_idx[c][rowin];
            #pragma unroll
            for (int nt = 0; nt < 4; nt++) {
                int col  = cw * 64 + nt * 16 + cc;
                float pe = pos_embed[rowin * 256 + col];
                float val = (rowin < m) ? v[((size_t)bi * 64 + vidx) * 256 + col] : 0.0f;
                xr[nt][rr] = val + pe;
            }
        }
    };

    // ---- layernorm: xr regs -> abuf (bf16, swizzled) ----
    auto do_ln = [&](const float* __restrict__ lw, const float* __restrict__ lb) {
        float sm[4], sq[4];
        #pragma unroll
        for (int rr = 0; rr < 4; rr++) {
            float s = 0.f, q = 0.f;
            #pragma unroll
            for (int nt = 0; nt < 4; nt++) {
                float x = xr[nt][rr];
                s += x; q += x * x;
            }
            sm[rr] = s; sq[rr] = q;
        }
        #pragma unroll
        for (int off = 1; off < 16; off <<= 1) {
            #pragma unroll
            for (int rr = 0; rr < 4; rr++) {
                sm[rr] += __shfl_xor(sm[rr], off);
                sq[rr] += __shfl_xor(sq[rr], off);
            }
        }
        if (cc == 0) {
            #pragma unroll
            for (int rr = 0; rr < 4; rr++) {
                int row = mrow0 + cq * 4 + rr;
                lnred[(cw * 32 + row) * 2 + 0] = sm[rr];
                lnred[(cw * 32 + row) * 2 + 1] = sq[rr];
            }
        }
        __syncthreads();
        float mu[4], rs[4];
        #pragma unroll
        for (int rr = 0; rr < 4; rr++) {
            int row = mrow0 + cq * 4 + rr;
            float S = 0.f, Q = 0.f;
            #pragma unroll
            for (int w = 0; w < 4; w++) {
                S += lnred[(w * 32 + row) * 2 + 0];
                Q += lnred[(w * 32 + row) * 2 + 1];
            }
            float m_ = S * (1.0f / 256.0f);
            mu[rr] = m_;
            rs[rr] = rsqrtf(Q * (1.0f / 256.0f) - m_ * m_ + 1e-5f);
        }
        #pragma unroll
        for (int nt = 0; nt < 4; nt++) {
            int col = cw * 64 + nt * 16 + cc;
            float w_ = lw[col], b_ = lb[col];
            #pragma unroll
            for (int rr = 0; rr < 4; rr++) {
                int row = mrow0 + cq * 4 + rr;
                abuf[aswz(row, col)] = f2bf((xr[nt][rr] - mu[rr]) * rs[rr] * w_ + b_);
            }
        }
        __syncthreads();
    };

    auto load_a_abuf = [&](short8 (&a0)[8]) {
        #pragma unroll
        for (int kt = 0; kt < 8; kt++)
            a0[kt] = *reinterpret_cast<const short8*>(&abuf[aswz(mrow0 + cc, kt * 32 + cq * 8)]);
    };

    // ---- gather #1 + LN1 ----
    do_gather();
    do_ln(ln1_w, ln1_b);

    // ---- GEMM1 (merged QKV, NT=12, 4-kt B groups, dbuf) ----
    {
        short8 a0[8];
        load_a_abuf(a0);
        __syncthreads();   // a-frags loaded before Vt overwrites abuf

        auto gbase = [&](int g) {
            int nt = g >> 1, kh = g & 1;
            int gnt = (nt < 8) ? (cw * 8 + nt) : (32 + cw * 4 + (nt - 8));
            return wb + G1_OFF + ((size_t)gnt * 8 + kh * 4) * 512 + lane * 8;
        };
        short8 bb[2][4];
        load_bgrp<4>(bb[0], gbase(0));
        f32x4 c0;
        #pragma unroll
        for (int nt = 0; nt < 12; nt++) {
            #pragma unroll
            for (int kh = 0; kh < 2; kh++) {
                int g = nt * 2 + kh;
                if (g + 1 < 24) load_bgrp<4>(bb[(g + 1) & 1], gbase(g + 1));
                if (kh == 0) {
                    float b = (nt < 8) ? in_proj_b[cw * 128 + nt * 16 + cc]
                                       : in_proj_b[512 + cw * 64 + (nt - 8) * 16 + cc];
                    c0 = (f32x4){b, b, b, b};
                }
                __builtin_amdgcn_s_setprio(1);
                #pragma unroll
                for (int kt = 0; kt < 4; kt++)
                    c0 = __builtin_amdgcn_mfma_f32_16x16x32_bf16(a0[kh * 4 + kt], bb[g & 1][kt], c0, 0, 0, 0);
                __builtin_amdgcn_s_setprio(0);
            }
            if (nt < 8) {
                int col = cw * 128 + nt * 16 + cc;
                #pragma unroll
                for (int r = 0; r < 4; r++)
                    qkbuf[qswz(mrow0 + cq * 4 + r, col)] = f2bf(c0[r]);
            } else {
                int d = cw * 64 + (nt - 8) * 16 + cc;
                short4v p0;
                #pragma unroll
                for (int r = 0; r < 4; r++) p0[r] = (short)f2bf(c0[r]);
                *reinterpret_cast<short4v*>(&abuf[vtswz(d, mrow0 + cq * 4)]) = p0;
            }
        }
    }
    __syncthreads();

    // ---- re-gather residual (overlaps attention) ----
    do_gather();

    // ---- attention scores (MFMA) + softmax -> P (wave = (pair, head)) ----
    {
        int pair = wid >> 2;   // 0..1
        int h    = wid & 3;    // 0..3
        f32x4 c = {0.f, 0.f, 0.f, 0.f};
        #pragma unroll
        for (int kt = 0; kt < 2; kt++) {
            short8 qa = *reinterpret_cast<const short8*>(&qkbuf[qswz(pair * 16 + cc, h * 64 + cq * 8 + kt * 32)]);
            short8 kb = *reinterpret_cast<const short8*>(&qkbuf[qswz(pair * 16 + cc, 256 + h * 64 + cq * 8 + kt * 32)]);
            c = __builtin_amdgcn_mfma_f32_16x16x32_bf16(qa, kb, c, 0, 0, 0);
        }
        int jhalf = cc >> 3, jloc = cc & 7;
        #pragma unroll
        for (int r = 0; r < 4; r++) {
            int q = cq * 4 + r;
            int qhalf = q >> 3;
            int m = s_m[pair * 2 + qhalf];
            bool valid = (jhalf == qhalf) && (jloc < m);
            float s = valid ? c[r] * 0.125f : -1e30f;
            float mx = s;
            mx = fmaxf(mx, __shfl_xor(mx, 1));
            mx = fmaxf(mx, __shfl_xor(mx, 2));
            mx = fmaxf(mx, __shfl_xor(mx, 4));
            float e = valid ? __expf(s - mx) : 0.f;
            float se = e;
            se += __shfl_xor(se, 1);
            se += __shfl_xor(se, 2);
            se += __shfl_xor(se, 4);
            attw_s[pair][h][q][cc] = f2bf((se > 0.f) ? e / se : 0.f);
        }
    }
    __syncthreads();

    // ---- PV (MFMA, K=32 zero-padded) -> ao (swizzled into qkbuf) ----
    {
        int pair = wid >> 2;
        int h    = wid & 3;
        int jbg  = pair * 16 + (cq & 1) * 8;
        short8 pa;
        if (cq < 2) pa = *reinterpret_cast<const short8*>(&attw_s[pair][h][cc][cq * 8]);
        else        pa = (short8)((short)0);
        #pragma unroll
        for (int t = 0; t < 4; t++) {
            int d = h * 64 + t * 16 + cc;
            short4v lo = *reinterpret_cast<const short4v*>(&abuf[vtswz(d, jbg)]);
            short4v hi = *reinterpret_cast<const short4v*>(&abuf[vtswz(d, jbg + 4)]);
            union { short8 vv; short4v half2[2]; } u;
            u.half2[0] = lo; u.half2[1] = hi;
            f32x4 c = {0.f, 0.f, 0.f, 0.f};
            c = __builtin_amdgcn_mfma_f32_16x16x32_bf16(pa, u.vv, c, 0, 0, 0);
            #pragma unroll
            for (int r = 0; r < 4; r++)
                qkbuf[qswz(pair * 16 + cq * 4 + r, d)] = f2bf(c[r]);
        }
    }
    __syncthreads();

    // ---- GEMM2: xr += ao @ W2^T + b2 (kh-outer, dbuf) ----
    {
        #pragma unroll
        for (int nt = 0; nt < 4; nt++) {
            float b = out_proj_b[cw * 64 + nt * 16 + cc];
            #pragma unroll
            for (int r = 0; r < 4; r++) xr[nt][r] += b;
        }
        auto gbase = [&](int g) {
            int kh = g >> 2, nt = g & 3;
            return wb + G2_OFF + ((size_t)(cw * 4 + nt) * 8 + kh * 4) * 512 + lane * 8;
        };
        short8 bb[2][4];
        load_bgrp<4>(bb[0], gbase(0));
        #pragma unroll
        for (int kh = 0; kh < 2; kh++) {
            short8 a0h[4];
            #pragma unroll
            for (int kt = 0; kt < 4; kt++)
                a0h[kt] = *reinterpret_cast<const short8*>(&qkbuf[qswz(mrow0 + cc, kh * 128 + kt * 32 + cq * 8)]);
            #pragma unroll
            for (int nt = 0; nt < 4; nt++) {
                int g = kh * 4 + nt;
                if (g + 1 < 8) load_bgrp<4>(bb[(g + 1) & 1], gbase(g + 1));
                __builtin_amdgcn_s_setprio(1);
                #pragma unroll
                for (int kt = 0; kt < 4; kt++)
                    xr[nt] = __builtin_amdgcn_mfma_f32_16x16x32_bf16(a0h[kt], bb[g & 1][kt], xr[nt], 0, 0, 0);
                __builtin_amdgcn_s_setprio(0);
            }
        }
    }
    __syncthreads();

    // ---- pool x2 -> px2 LDS ----
    {
        int c = mg * 2 + (cq >> 1);
        int m = s_m[c];
        #pragma unroll
        for (int nt = 0; nt < 4; nt++) {
            float p = 0.f;
            #pragma unroll
            for (int rr = 0; rr < 4; rr++)
                if ((cq & 1) * 4 + rr < m) p += xr[nt][rr];
            p += __shfl_xor(p, 16);
            if ((cq & 1) == 0) {
                int col = cw * 64 + nt * 16 + cc;
                px2[c * PX2_ST + col] = p;
            }
        }
    }

    // ---- LN2 ----
    do_ln(ln2_w, ln2_b);

    // ---- GEMM3: gelu(h2 @ W3^T + b3) pooled on the fly -> pgff (NT=8) ----
    {
        short8 a0[8];
        load_a_abuf(a0);
        auto gbase = [&](int g) {
            int nt = g >> 1, kh = g & 1;
            return wb + G3_OFF + ((size_t)(cw * 8 + nt) * 8 + kh * 4) * 512 + lane * 8;
        };
        short8 bb[2][4];
        load_bgrp<4>(bb[0], gbase(0));
        f32x4 c0;
        #pragma unroll
        for (int nt = 0; nt < 8; nt++) {
            #pragma unroll
            for (int kh = 0; kh < 2; kh++) {
                int g = nt * 2 + kh;
                if (g + 1 < 16) load_bgrp<4>(bb[(g + 1) & 1], gbase(g + 1));
                if (kh == 0) {
                    float b = ff1_b[cw * 128 + nt * 16 + cc];
                    c0 = (f32x4){b, b, b, b};
                }
                __builtin_amdgcn_s_setprio(1);
                #pragma unroll
                for (int kt = 0; kt < 4; kt++)
                    c0 = __builtin_amdgcn_mfma_f32_16x16x32_bf16(a0[kh * 4 + kt], bb[g & 1][kt], c0, 0, 0, 0);
                __builtin_amdgcn_s_setprio(0);
            }
            // epilogue: gelu + masked row-sum -> pgff
            int col = cw * 128 + nt * 16 + cc;
            int c   = mg * 2 + (cq >> 1);
            int m0  = s_m[c];
            float s0 = 0.f;
            #pragma unroll
            for (int r = 0; r < 4; r++) {
                float g0 = gelu_f(c0[r]);
                if ((cq & 1) * 4 + r < m0) s0 += g0;
            }
            s0 += __shfl_xor(s0, 16);
            if ((cq & 1) == 0)
                pgff[c * PGF_ST + col] = s0;
        }
    }
    __syncthreads();

    // ---- GEMV4 (4-row MFMA): pooled = (px2 + pgff @ W4^T)/m + b4 (2 nt/wave) ----
    {
        auto gbase = [&](int g) {
            int kh = g >> 1, j = g & 1;
            return wb + G4_OFF + ((size_t)(wid * 2 + j) * 16 + kh * 4) * 512 + lane * 8;
        };
        short8 bb[2][4];
        load_bgrp<4>(bb[0], gbase(0));
        f32x4 acc[2];
        acc[0] = (f32x4){0.f, 0.f, 0.f, 0.f};
        acc[1] = (f32x4){0.f, 0.f, 0.f, 0.f};
        #pragma unroll
        for (int kh = 0; kh < 4; kh++) {
            short8 af[4];
            #pragma unroll
            for (int kt = 0; kt < 4; kt++) {
                short8 t = (short8)((short)0);
                if (cc < 4) {
                    const float4* s4 = reinterpret_cast<const float4*>(&pgff[cc * PGF_ST + (kh * 4 + kt) * 32 + cq * 8]);
                    float4 x0 = s4[0];
                    float4 x1 = s4[1];
                    t[0] = (short)f2bf(x0.x); t[1] = (short)f2bf(x0.y);
                    t[2] = (short)f2bf(x0.z); t[3] = (short)f2bf(x0.w);
                    t[4] = (short)f2bf(x1.x); t[5] = (short)f2bf(x1.y);
                    t[6] = (short)f2bf(x1.z); t[7] = (short)f2bf(x1.w);
                }
                af[kt] = t;
            }
            #pragma unroll
            for (int j = 0; j < 2; j++) {
                int g = kh * 2 + j;
                if (g + 1 < 8) load_bgrp<4>(bb[(g + 1) & 1], gbase(g + 1));
                __builtin_amdgcn_s_setprio(1);
                #pragma unroll
                for (int kt = 0; kt < 4; kt++)
                    acc[j] = __builtin_amdgcn_mfma_f32_16x16x32_bf16(af[kt], bb[g & 1][kt], acc[j], 0, 0, 0);
                __builtin_amdgcn_s_setprio(0);
            }
        }
        if (cq == 0) {
            #pragma unroll
            for (int j = 0; j < 2; j++) {
                int col = (wid * 2 + j) * 16 + cc;
                float b4 = ff2_b[col];
                #pragma unroll
                for (int r = 0; r < 4; r++) {
                    int m = s_m[r];
                    float val = 0.f;
                    if (m > 0) val = (px2[r * PX2_ST + col] + acc[j][r]) / (float)m + b4;
                    out[(size_t)(cg0 + r) * 256 + col] = val;
                }
            }
        }
    }
}

// ===================== head kernel (32 chunks/block, MFMA) =====================
__global__ __launch_bounds__(256, 2)
void tsa_head(const float* __restrict__ count,
              const float* __restrict__ o1_b, const float* __restrict__ o2_b,
              const unsigned short* __restrict__ wb, const float* __restrict__ w256,
              float* __restrict__ out)
{
    __shared__ unsigned short fbuf[32 * 256];
    __shared__ unsigned short gbuf[32 * 512];
    __shared__ float cbuf[32];

    const int tid  = threadIdx.x;
    const int lane = tid & 63;
    const int wid  = tid >> 6;
    const int cq   = lane >> 4;
    const int cc   = lane & 15;
    const int c0b  = blockIdx.x * 32;

    for (int i = tid; i < 32 * 256; i += 256) {
        int row = i >> 8, col = i & 255;
        fbuf[aswz(row, col)] = f2bf(out[(size_t)(c0b + row) * 256 + col]);
    }
    if (tid < 32) cbuf[tid] = log1pf(count[c0b + tid]);
    __syncthreads();

    // ---- o1: g1 = gelu(feat @ o1_w^T + cnt*w256 + b) (kh-split, dbuf) ----
    {
        auto gbase = [&](int g) {
            int nt = g >> 1, kh = g & 1;
            return wb + O1_OFF + ((size_t)(wid * 8 + nt) * 8 + kh * 4) * 512 + lane * 8;
        };
        short8 a0[8], a1[8];
        #pragma unroll
        for (int kt = 0; kt < 8; kt++) {
            a0[kt] = *reinterpret_cast<const short8*>(&fbuf[aswz(cc,      kt * 32 + cq * 8)]);
            a1[kt] = *reinterpret_cast<const short8*>(&fbuf[aswz(16 + cc, kt * 32 + cq * 8)]);
        }
        short8 bb[2][4];
        load_bgrp<4>(bb[0], gbase(0));
        f32x4 c0, c1;
        #pragma unroll
        for (int nt = 0; nt < 8; nt++) {
            #pragma unroll
            for (int kh = 0; kh < 2; kh++) {
                int g = nt * 2 + kh;
                if (g + 1 < 16) load_bgrp<4>(bb[(g + 1) & 1], gbase(g + 1));
                if (kh == 0) {
                    float b = o1_b[wid * 128 + nt * 16 + cc];
                    c0 = (f32x4){b, b, b, b};
                    c1 = (f32x4){b, b, b, b};
                }
                __builtin_amdgcn_s_setprio(1);
                #pragma unroll
                for (int kt = 0; kt < 4; kt++) {
                    c0 = __builtin_amdgcn_mfma_f32_16x16x32_bf16(a0[kh * 4 + kt], bb[g & 1][kt], c0, 0, 0, 0);
                    c1 = __builtin_amdgcn_mfma_f32_16x16x32_bf16(a1[kh * 4 + kt], bb[g & 1][kt], c1, 0, 0, 0);
                }
                __builtin_amdgcn_s_setprio(0);
            }
            int col  = wid * 128 + nt * 16 + cc;
            float wc = w256[col];
            #pragma unroll
            for (int r = 0; r < 4; r++) {
                int r0 = cq * 4 + r, r1 = 16 + cq * 4 + r;
                gbuf[qswz(r0, col)] = f2bf(gelu_f(c0[r] + cbuf[r0] * wc));
                gbuf[qswz(r1, col)] = f2bf(gelu_f(c1[r] + cbuf[r1] * wc));
            }
        }
    }
    __syncthreads();

    // ---- o2: out = g1 @ o2_w^T + b (K=512, kh-outer quarters) ----
    {
        f32x4 c[4][2];
        #pragma unroll
        for (int nt = 0; nt < 4; nt++) {
            float b = o2_b[wid * 64 + nt * 16 + cc];
            c[nt][0] = (f32x4){b, b, b, b};
            c[nt][1] = (f32x4){b, b, b, b};
        }
        auto gbase = [&](int g) {
            int half = g >> 3, kh = (g >> 2) & 1, nt = g & 3;
            return wb + O2_OFF + ((size_t)(wid * 4 + nt) * 16 + half * 8 + kh * 4) * 512 + lane * 8;
        };
        short8 bb[2][4];
        load_bgrp<4>(bb[0], gbase(0));
        #pragma unroll
        for (int half = 0; half < 2; half++) {
            #pragma unroll
            for (int kh = 0; kh < 2; kh++) {
                short8 a0q[4], a1q[4];
                #pragma unroll
                for (int kt = 0; kt < 4; kt++) {
                    int scol = half * 256 + kh * 128 + kt * 32 + cq * 8;
                    a0q[kt] = *reinterpret_cast<const short8*>(&gbuf[qswz(cc,      scol)]);
                    a1q[kt] = *reinterpret_cast<const short8*>(&gbuf[qswz(16 + cc, scol)]);
                }
                #pragma unroll
                for (int nt = 0; nt < 4; nt++) {
                    int g = half * 8 + kh * 4 + nt;
                    if (g + 1 < 16) load_bgrp<4>(bb[(g + 1) & 1], gbase(g + 1));
                    __builtin_amdgcn_s_setprio(1);
                    #pragma unroll
                    for (int kt = 0; kt < 4; kt++) {
                        c[nt][0] = __builtin_amdgcn_mfma_f32_16x16x32_bf16(a0q[kt], bb[g & 1][kt], c[nt][0], 0, 0, 0);
                        c[nt][1] = __builtin_amdgcn_mfma_f32_16x16x32_bf16(a1q[kt], bb[g & 1][kt], c[nt][1], 0, 0, 0);
                    }
                    __builtin_amdgcn_s_setprio(0);
                }
            }
        }
        #pragma unroll
        for (int nt = 0; nt < 4; nt++) {
            int col = wid * 64 + nt * 16 + cc;
            #pragma unroll
            for (int r = 0; r < 4; r++) {
                out[(size_t)(c0b + cq * 4 + r) * 256 + col]      = c[nt][0][r];
                out[(size_t)(c0b + 16 + cq * 4 + r) * 256 + col] = c[nt][1][r];
            }
        }
    }
}

extern "C" void kernel_launch(void* const* d_in, const int* in_sizes, int n_in,
                              void* d_out, int out_size, void* d_ws, size_t ws_size,
                              hipStream_t stream) {
    const float* v          = (const float*)d_in[0];
    const int*   batch_idx  = (const int*)d_in[1];
    const void*  mask       = d_in[2];
    const float* count      = (const float*)d_in[3];
    const float* pos_embed  = (const float*)d_in[4];
    const float* ln1_w      = (const float*)d_in[5];
    const float* ln1_b      = (const float*)d_in[6];
    const float* in_proj_w  = (const float*)d_in[7];
    const float* in_proj_b  = (const float*)d_in[8];
    const float* out_proj_w = (const float*)d_in[9];
    const float* out_proj_b = (const float*)d_in[10];
    const float* ln2_w      = (const float*)d_in[11];
    const float* ln2_b      = (const float*)d_in[12];
    const float* ff1_w      = (const float*)d_in[13];
    const float* ff1_b      = (const float*)d_in[14];
    const float* ff2_w      = (const float*)d_in[15];
    const float* ff2_b      = (const float*)d_in[16];
    const float* o1_w       = (const float*)d_in[17];
    const float* o1_b       = (const float*)d_in[18];
    const float* o2_w       = (const float*)d_in[19];
    const float* o2_b       = (const float*)d_in[20];
    float* out = (float*)d_out;

    unsigned short* wb = (unsigned short*)d_ws;
    float* w256 = (float*)((char*)d_ws + W256_BYTE_OFF);
    int* flag   = (int*)((char*)d_ws + FLAG_BYTE_OFF);

    conv_weights<<<387, 256, 0, stream>>>(in_proj_w, out_proj_w, ff1_w, ff2_w, o1_w, o2_w, wb, w256);
    detect_mask_fmt<<<1, 256, 0, stream>>>((const unsigned int*)mask, 16384, flag);
    tsa_main<<<NCC / G, 512, 0, stream>>>(v, batch_idx, mask, pos_embed,
                                          ln1_w, ln1_b, in_proj_b, out_proj_b,
                                          ln2_w, ln2_b, ff1_b, ff2_b,
                                          wb, flag, out);
    tsa_head<<<NCC / 32, 256, 0, stream>>>(count, o1_b, o2_b, wb, w256, out);
}

// Round 15
// 823.424 us; speedup vs baseline: 1.0006x; 1.0006x over previous
//
#include <hip/hip_runtime.h>
#include <hip/hip_bf16.h>
#include <math.h>

typedef short short8 __attribute__((ext_vector_type(8)));
typedef short short4v __attribute__((ext_vector_type(4)));
typedef float f32x4 __attribute__((ext_vector_type(4)));

#define NCC  32768
#define G    4

// swizzled-weight region offsets in d_ws (units: unsigned short)
#define G1_OFF 0        // in_proj  768x256
#define G2_OFF 196608   // out_proj 256x256
#define G3_OFF 262144   // ff1      512x256
#define G4_OFF 393216   // ff2      256x512
#define O1_OFF 524288   // o1 (first 256 of K=257) 512x256
#define O2_OFF 655360   // o2       256x512
#define SWZ_SHORTS 786432
#define W256_BYTE_OFF (SWZ_SHORTS * 2)
#define FLAG_BYTE_OFF (W256_BYTE_OFF + 2048)

// padded LDS strides (f32) for pool buffers
#define PX2_ST 260
#define PGF_ST 520

__device__ __forceinline__ float gelu_f(float x) {
    return x * 0.5f * (1.0f + erff(x * 0.70710678118654752f));
}
__device__ __forceinline__ unsigned short f2bf(float f) {
    __hip_bfloat16 h = __float2bfloat16(f);
    return *reinterpret_cast<unsigned short*>(&h);
}
__device__ __forceinline__ int aswz(int row, int scol) {
    return row * 256 + (scol ^ ((row & 7) << 3));
}
__device__ __forceinline__ int qswz(int row, int scol) {
    return row * 512 + (scol ^ ((row & 7) << 3));
}
__device__ __forceinline__ int vtswz(int d, int j) {
    return d * 32 + (j ^ ((d & 7) << 2));
}

template<int KTS>
__device__ __forceinline__ void load_bgrp(short8 (&b)[KTS], const unsigned short* __restrict__ base) {
    #pragma unroll
    for (int kt = 0; kt < KTS; kt++)
        b[kt] = *reinterpret_cast<const short8*>(base + (size_t)kt * 512);
}

// ---- one-time weight swizzle into MFMA B-fragment order ----
__global__ void conv_weights(const float* __restrict__ w1, const float* __restrict__ w2,
                             const float* __restrict__ w3, const float* __restrict__ w4,
                             const float* __restrict__ o1, const float* __restrict__ o2,
                             unsigned short* __restrict__ dst, float* __restrict__ w256) {
    int i = blockIdx.x * 256 + threadIdx.x;
    if (i < 98304) {
        const float* src; int kts, sk, base;
        if (i < 24576)      { src = w1; kts = 8;  sk = 256; base = 0; }
        else if (i < 32768) { src = w2; kts = 8;  sk = 256; base = 24576; }
        else if (i < 49152) { src = w3; kts = 8;  sk = 256; base = 32768; }
        else if (i < 65536) { src = w4; kts = 16; sk = 512; base = 49152; }
        else if (i < 81920) { src = o1; kts = 8;  sk = 257; base = 65536; }
        else                { src = o2; kts = 16; sk = 512; base = 81920; }
        int li   = i - base;
        int lane = li & 63;
        int fi   = li >> 6;
        int kt   = fi % kts;
        int nt   = fi / kts;
        int col  = nt * 16 + (lane & 15);
        int k    = kt * 32 + (lane >> 4) * 8;
        const float* s = src + (size_t)col * sk + k;
        unsigned short* d = dst + (size_t)i * 8;
        #pragma unroll
        for (int e = 0; e < 8; e++) d[e] = f2bf(s[e]);
    } else if (i < 98816) {
        int c = i - 98304;
        w256[c] = o1[(size_t)c * 257 + 256];
    }
}

// ---- mask storage format detect: 0=int32, 1=byte, 2=float32 ----
__global__ void detect_mask_fmt(const unsigned int* __restrict__ mw, int nwords, int* __restrict__ flag) {
    __shared__ int s_bad_int, s_bad_float;
    if (threadIdx.x == 0) { s_bad_int = 0; s_bad_float = 0; }
    __syncthreads();
    int bad_int = 0, bad_float = 0;
    for (int i = threadIdx.x; i < nwords; i += blockDim.x) {
        unsigned int w = mw[i];
        if (w > 1u) bad_int = 1;
        if (w != 0u && w != 0x3F800000u) bad_float = 1;
    }
    if (bad_int)   atomicOr(&s_bad_int, 1);
    if (bad_float) atomicOr(&s_bad_float, 1);
    __syncthreads();
    if (threadIdx.x == 0)
        *flag = (!s_bad_int) ? 0 : ((!s_bad_float) ? 2 : 1);
}

// ===================== main transformer kernel =====================
// 512 threads (8 waves), G=4. Per-wave tile: 1 M-tile (16 rows) x 64 cols.
// launch_bounds(512,2): budget = 256/2 = 128 total regs/wave (ladder law) ->
// live set ~100 fits, no spill; HW then allows 4 waves/SIMD; LDS allows
// 2 blocks/CU -> 16 waves/CU (2x R12 occupancy).
__global__ __launch_bounds__(512, 2)
void tsa_main(const float* __restrict__ v,
              const int* __restrict__ batch_idx,
              const void* __restrict__ mask,
              const float* __restrict__ pos_embed,
              const float* __restrict__ ln1_w, const float* __restrict__ ln1_b,
              const float* __restrict__ in_proj_b,
              const float* __restrict__ out_proj_b,
              const float* __restrict__ ln2_w, const float* __restrict__ ln2_b,
              const float* __restrict__ ff1_b, const float* __restrict__ ff2_b,
              const unsigned short* __restrict__ wb,
              const int* __restrict__ mask_flag,
              float* __restrict__ out)
{
    __shared__ unsigned short qkbuf[32 * 512];      // lnred | Q|K -> ao | px2 | pgff
    __shared__ unsigned short abuf[32 * 256];       // LN1(swz) -> Vt(swz) -> LN2(swz)
    __shared__ unsigned short attw_s[2][4][16][16]; // P (bf16)
    __shared__ int s_idx[G][8];
    __shared__ int s_m[G];
    __shared__ int s_bi[G];

    float* lnred = reinterpret_cast<float*>(qkbuf);           // bytes 0..2048
    float* px2   = reinterpret_cast<float*>(qkbuf + 2048);    // bytes 4096..8256
    float* pgff  = reinterpret_cast<float*>(qkbuf + 8192);    // bytes 16384..24704

    const int tid  = threadIdx.x;
    const int lane = tid & 63;
    const int wid  = tid >> 6;       // 0..7
    const int cw   = wid & 3;        // N-quarter: cols cw*64..
    const int mg   = wid >> 2;       // M-half: rows mg*16..
    const int mrow0 = mg * 16;
    const int cq   = lane >> 4;
    const int cc   = lane & 15;
    const int cg0  = blockIdx.x * G;

    f32x4 xr[4];   // residual: row = mrow0+cq*4+r, col = cw*64+nt*16+cc

    // ---- mask parse (waves 0..3 -> chunk wid) ----
    if (wid < G) {
        int mf = *mask_flag;
        size_t base = (size_t)(cg0 + wid) * 64 + lane;
        int bit;
        if (mf == 0)      bit = ((const int*)mask)[base] != 0;
        else if (mf == 2) bit = ((const float*)mask)[base] != 0.0f;
        else              bit = ((const unsigned char*)mask)[base] != 0;
        unsigned long long bal = __ballot(bit);
        if (lane == 0) {
            int mm = 0; unsigned long long b = bal;
            while (b && mm < 8) { s_idx[wid][mm++] = __ffsll(b) - 1; b &= (b - 1); }
            for (int t = mm; t < 8; t++) s_idx[wid][t] = 0;
            s_m[wid]  = mm;
            s_bi[wid] = batch_idx[cg0 + wid];
        }
    }
    __syncthreads();

    // ---- gather helper: v+pos -> xr regs (16 rows x 64 cols per wave) ----
    auto do_gather = [&]() {
        int c  = mg * 2 + (cq >> 1);
        int m  = s_m[c];
        int bi = s_bi[c];
        #pragma unroll
        for (int rr = 0; rr < 4; rr++) {
            int rowin = (cq & 1) * 4 + rr;
            int vidx  = s_idx[c][rowin];
            #pragma unroll
            for (int nt = 0; nt < 4; nt++) {
                int col  = cw * 64 + nt * 16 + cc;
                float pe = pos_embed[rowin * 256 + col];
                float val = (rowin < m) ? v[((size_t)bi * 64 + vidx) * 256 + col] : 0.0f;
                xr[nt][rr] = val + pe;
            }
        }
    };

    // ---- layernorm: xr regs -> abuf (bf16, swizzled) ----
    auto do_ln = [&](const float* __restrict__ lw, const float* __restrict__ lb) {
        float sm[4], sq[4];
        #pragma unroll
        for (int rr = 0; rr < 4; rr++) {
            float s = 0.f, q = 0.f;
            #pragma unroll
            for (int nt = 0; nt < 4; nt++) {
                float x = xr[nt][rr];
                s += x; q += x * x;
            }
            sm[rr] = s; sq[rr] = q;
        }
        #pragma unroll
        for (int off = 1; off < 16; off <<= 1) {
            #pragma unroll
            for (int rr = 0; rr < 4; rr++) {
                sm[rr] += __shfl_xor(sm[rr], off);
                sq[rr] += __shfl_xor(sq[rr], off);
            }
        }
        if (cc == 0) {
            #pragma unroll
            for (int rr = 0; rr < 4; rr++) {
                int row = mrow0 + cq * 4 + rr;
                lnred[(cw * 32 + row) * 2 + 0] = sm[rr];
                lnred[(cw * 32 + row) * 2 + 1] = sq[rr];
            }
        }
        __syncthreads();
        float mu[4], rs[4];
        #pragma unroll
        for (int rr = 0; rr < 4; rr++) {
            int row = mrow0 + cq * 4 + rr;
            float S = 0.f, Q = 0.f;
            #pragma unroll
            for (int w = 0; w < 4; w++) {
                S += lnred[(w * 32 + row) * 2 + 0];
                Q += lnred[(w * 32 + row) * 2 + 1];
            }
            float m_ = S * (1.0f / 256.0f);
            mu[rr] = m_;
            rs[rr] = rsqrtf(Q * (1.0f / 256.0f) - m_ * m_ + 1e-5f);
        }
        #pragma unroll
        for (int nt = 0; nt < 4; nt++) {
            int col = cw * 64 + nt * 16 + cc;
            float w_ = lw[col], b_ = lb[col];
            #pragma unroll
            for (int rr = 0; rr < 4; rr++) {
                int row = mrow0 + cq * 4 + rr;
                abuf[aswz(row, col)] = f2bf((xr[nt][rr] - mu[rr]) * rs[rr] * w_ + b_);
            }
        }
        __syncthreads();
    };

    auto load_a_abuf = [&](short8 (&a0)[8]) {
        #pragma unroll
        for (int kt = 0; kt < 8; kt++)
            a0[kt] = *reinterpret_cast<const short8*>(&abuf[aswz(mrow0 + cc, kt * 32 + cq * 8)]);
    };

    // ---- gather #1 + LN1 ----
    do_gather();
    do_ln(ln1_w, ln1_b);

    // ---- GEMM1 (merged QKV, NT=12, 4-kt B groups, dbuf) ----
    {
        short8 a0[8];
        load_a_abuf(a0);
        __syncthreads();   // a-frags loaded before Vt overwrites abuf

        auto gbase = [&](int g) {
            int nt = g >> 1, kh = g & 1;
            int gnt = (nt < 8) ? (cw * 8 + nt) : (32 + cw * 4 + (nt - 8));
            return wb + G1_OFF + ((size_t)gnt * 8 + kh * 4) * 512 + lane * 8;
        };
        short8 bb[2][4];
        load_bgrp<4>(bb[0], gbase(0));
        f32x4 c0;
        #pragma unroll
        for (int nt = 0; nt < 12; nt++) {
            #pragma unroll
            for (int kh = 0; kh < 2; kh++) {
                int g = nt * 2 + kh;
                if (g + 1 < 24) load_bgrp<4>(bb[(g + 1) & 1], gbase(g + 1));
                if (kh == 0) {
                    float b = (nt < 8) ? in_proj_b[cw * 128 + nt * 16 + cc]
                                       : in_proj_b[512 + cw * 64 + (nt - 8) * 16 + cc];
                    c0 = (f32x4){b, b, b, b};
                }
                __builtin_amdgcn_s_setprio(1);
                #pragma unroll
                for (int kt = 0; kt < 4; kt++)
                    c0 = __builtin_amdgcn_mfma_f32_16x16x32_bf16(a0[kh * 4 + kt], bb[g & 1][kt], c0, 0, 0, 0);
                __builtin_amdgcn_s_setprio(0);
            }
            if (nt < 8) {
                int col = cw * 128 + nt * 16 + cc;
                #pragma unroll
                for (int r = 0; r < 4; r++)
                    qkbuf[qswz(mrow0 + cq * 4 + r, col)] = f2bf(c0[r]);
            } else {
                int d = cw * 64 + (nt - 8) * 16 + cc;
                short4v p0;
                #pragma unroll
                for (int r = 0; r < 4; r++) p0[r] = (short)f2bf(c0[r]);
                *reinterpret_cast<short4v*>(&abuf[vtswz(d, mrow0 + cq * 4)]) = p0;
            }
        }
    }
    __syncthreads();

    // ---- re-gather residual (overlaps attention) ----
    do_gather();

    // ---- attention scores (MFMA) + softmax -> P (wave = (pair, head)) ----
    {
        int pair = wid >> 2;   // 0..1
        int h    = wid & 3;    // 0..3
        f32x4 c = {0.f, 0.f, 0.f, 0.f};
        #pragma unroll
        for (int kt = 0; kt < 2; kt++) {
            short8 qa = *reinterpret_cast<const short8*>(&qkbuf[qswz(pair * 16 + cc, h * 64 + cq * 8 + kt * 32)]);
            short8 kb = *reinterpret_cast<const short8*>(&qkbuf[qswz(pair * 16 + cc, 256 + h * 64 + cq * 8 + kt * 32)]);
            c = __builtin_amdgcn_mfma_f32_16x16x32_bf16(qa, kb, c, 0, 0, 0);
        }
        int jhalf = cc >> 3, jloc = cc & 7;
        #pragma unroll
        for (int r = 0; r < 4; r++) {
            int q = cq * 4 + r;
            int qhalf = q >> 3;
            int m = s_m[pair * 2 + qhalf];
            bool valid = (jhalf == qhalf) && (jloc < m);
            float s = valid ? c[r] * 0.125f : -1e30f;
            float mx = s;
            mx = fmaxf(mx, __shfl_xor(mx, 1));
            mx = fmaxf(mx, __shfl_xor(mx, 2));
            mx = fmaxf(mx, __shfl_xor(mx, 4));
            float e = valid ? __expf(s - mx) : 0.f;
            float se = e;
            se += __shfl_xor(se, 1);
            se += __shfl_xor(se, 2);
            se += __shfl_xor(se, 4);
            attw_s[pair][h][q][cc] = f2bf((se > 0.f) ? e / se : 0.f);
        }
    }
    __syncthreads();

    // ---- PV (MFMA, K=32 zero-padded) -> ao (swizzled into qkbuf) ----
    {
        int pair = wid >> 2;
        int h    = wid & 3;
        int jbg  = pair * 16 + (cq & 1) * 8;
        short8 pa;
        if (cq < 2) pa = *reinterpret_cast<const short8*>(&attw_s[pair][h][cc][cq * 8]);
        else        pa = (short8)((short)0);
        #pragma unroll
        for (int t = 0; t < 4; t++) {
            int d = h * 64 + t * 16 + cc;
            short4v lo = *reinterpret_cast<const short4v*>(&abuf[vtswz(d, jbg)]);
            short4v hi = *reinterpret_cast<const short4v*>(&abuf[vtswz(d, jbg + 4)]);
            union { short8 vv; short4v half2[2]; } u;
            u.half2[0] = lo; u.half2[1] = hi;
            f32x4 c = {0.f, 0.f, 0.f, 0.f};
            c = __builtin_amdgcn_mfma_f32_16x16x32_bf16(pa, u.vv, c, 0, 0, 0);
            #pragma unroll
            for (int r = 0; r < 4; r++)
                qkbuf[qswz(pair * 16 + cq * 4 + r, d)] = f2bf(c[r]);
        }
    }
    __syncthreads();

    // ---- GEMM2: xr += ao @ W2^T + b2 (kh-outer, dbuf) ----
    {
        #pragma unroll
        for (int nt = 0; nt < 4; nt++) {
            float b = out_proj_b[cw * 64 + nt * 16 + cc];
            #pragma unroll
            for (int r = 0; r < 4; r++) xr[nt][r] += b;
        }
        auto gbase = [&](int g) {
            int kh = g >> 2, nt = g & 3;
            return wb + G2_OFF + ((size_t)(cw * 4 + nt) * 8 + kh * 4) * 512 + lane * 8;
        };
        short8 bb[2][4];
        load_bgrp<4>(bb[0], gbase(0));
        #pragma unroll
        for (int kh = 0; kh < 2; kh++) {
            short8 a0h[4];
            #pragma unroll
            for (int kt = 0; kt < 4; kt++)
                a0h[kt] = *reinterpret_cast<const short8*>(&qkbuf[qswz(mrow0 + cc, kh * 128 + kt * 32 + cq * 8)]);
            #pragma unroll
            for (int nt = 0; nt < 4; nt++) {
                int g = kh * 4 + nt;
                if (g + 1 < 8) load_bgrp<4>(bb[(g + 1) & 1], gbase(g + 1));
                __builtin_amdgcn_s_setprio(1);
                #pragma unroll
                for (int kt = 0; kt < 4; kt++)
                    xr[nt] = __builtin_amdgcn_mfma_f32_16x16x32_bf16(a0h[kt], bb[g & 1][kt], xr[nt], 0, 0, 0);
                __builtin_amdgcn_s_setprio(0);
            }
        }
    }
    __syncthreads();

    // ---- pool x2 -> px2 LDS ----
    {
        int c = mg * 2 + (cq >> 1);
        int m = s_m[c];
        #pragma unroll
        for (int nt = 0; nt < 4; nt++) {
            float p = 0.f;
            #pragma unroll
            for (int rr = 0; rr < 4; rr++)
                if ((cq & 1) * 4 + rr < m) p += xr[nt][rr];
            p += __shfl_xor(p, 16);
            if ((cq & 1) == 0) {
                int col = cw * 64 + nt * 16 + cc;
                px2[c * PX2_ST + col] = p;
            }
        }
    }

    // ---- LN2 ----
    do_ln(ln2_w, ln2_b);

    // ---- GEMM3: gelu(h2 @ W3^T + b3) pooled on the fly -> pgff (NT=8) ----
    {
        short8 a0[8];
        load_a_abuf(a0);
        auto gbase = [&](int g) {
            int nt = g >> 1, kh = g & 1;
            return wb + G3_OFF + ((size_t)(cw * 8 + nt) * 8 + kh * 4) * 512 + lane * 8;
        };
        short8 bb[2][4];
        load_bgrp<4>(bb[0], gbase(0));
        f32x4 c0;
        #pragma unroll
        for (int nt = 0; nt < 8; nt++) {
            #pragma unroll
            for (int kh = 0; kh < 2; kh++) {
                int g = nt * 2 + kh;
                if (g + 1 < 16) load_bgrp<4>(bb[(g + 1) & 1], gbase(g + 1));
                if (kh == 0) {
                    float b = ff1_b[cw * 128 + nt * 16 + cc];
                    c0 = (f32x4){b, b, b, b};
                }
                __builtin_amdgcn_s_setprio(1);
                #pragma unroll
                for (int kt = 0; kt < 4; kt++)
                    c0 = __builtin_amdgcn_mfma_f32_16x16x32_bf16(a0[kh * 4 + kt], bb[g & 1][kt], c0, 0, 0, 0);
                __builtin_amdgcn_s_setprio(0);
            }
            // epilogue: gelu + masked row-sum -> pgff
            int col = cw * 128 + nt * 16 + cc;
            int c   = mg * 2 + (cq >> 1);
            int m0  = s_m[c];
            float s0 = 0.f;
            #pragma unroll
            for (int r = 0; r < 4; r++) {
                float g0 = gelu_f(c0[r]);
                if ((cq & 1) * 4 + r < m0) s0 += g0;
            }
            s0 += __shfl_xor(s0, 16);
            if ((cq & 1) == 0)
                pgff[c * PGF_ST + col] = s0;
        }
    }
    __syncthreads();

    // ---- GEMV4 (4-row MFMA): pooled = (px2 + pgff @ W4^T)/m + b4 (2 nt/wave) ----
    {
        auto gbase = [&](int g) {
            int kh = g >> 1, j = g & 1;
            return wb + G4_OFF + ((size_t)(wid * 2 + j) * 16 + kh * 4) * 512 + lane * 8;
        };
        short8 bb[2][4];
        load_bgrp<4>(bb[0], gbase(0));
        f32x4 acc[2];
        acc[0] = (f32x4){0.f, 0.f, 0.f, 0.f};
        acc[1] = (f32x4){0.f, 0.f, 0.f, 0.f};
        #pragma unroll
        for (int kh = 0; kh < 4; kh++) {
            short8 af[4];
            #pragma unroll
            for (int kt = 0; kt < 4; kt++) {
                short8 t = (short8)((short)0);
                if (cc < 4) {
                    const float4* s4 = reinterpret_cast<const float4*>(&pgff[cc * PGF_ST + (kh * 4 + kt) * 32 + cq * 8]);
                    float4 x0 = s4[0];
                    float4 x1 = s4[1];
                    t[0] = (short)f2bf(x0.x); t[1] = (short)f2bf(x0.y);
                    t[2] = (short)f2bf(x0.z); t[3] = (short)f2bf(x0.w);
                    t[4] = (short)f2bf(x1.x); t[5] = (short)f2bf(x1.y);
                    t[6] = (short)f2bf(x1.z); t[7] = (short)f2bf(x1.w);
                }
                af[kt] = t;
            }
            #pragma unroll
            for (int j = 0; j < 2; j++) {
                int g = kh * 2 + j;
                if (g + 1 < 8) load_bgrp<4>(bb[(g + 1) & 1], gbase(g + 1));
                __builtin_amdgcn_s_setprio(1);
                #pragma unroll
                for (int kt = 0; kt < 4; kt++)
                    acc[j] = __builtin_amdgcn_mfma_f32_16x16x32_bf16(af[kt], bb[g & 1][kt], acc[j], 0, 0, 0);
                __builtin_amdgcn_s_setprio(0);
            }
        }
        if (cq == 0) {
            #pragma unroll
            for (int j = 0; j < 2; j++) {
                int col = (wid * 2 + j) * 16 + cc;
                float b4 = ff2_b[col];
                #pragma unroll
                for (int r = 0; r < 4; r++) {
                    int m = s_m[r];
                    float val = 0.f;
                    if (m > 0) val = (px2[r * PX2_ST + col] + acc[j][r]) / (float)m + b4;
                    out[(size_t)(cg0 + r) * 256 + col] = val;
                }
            }
        }
    }
}

// ===================== head kernel (32 chunks/block, MFMA) =====================
__global__ __launch_bounds__(256, 2)
void tsa_head(const float* __restrict__ count,
              const float* __restrict__ o1_b, const float* __restrict__ o2_b,
              const unsigned short* __restrict__ wb, const float* __restrict__ w256,
              float* __restrict__ out)
{
    __shared__ unsigned short fbuf[32 * 256];
    __shared__ unsigned short gbuf[32 * 512];
    __shared__ float cbuf[32];

    const int tid  = threadIdx.x;
    const int lane = tid & 63;
    const int wid  = tid >> 6;
    const int cq   = lane >> 4;
    const int cc   = lane & 15;
    const int c0b  = blockIdx.x * 32;

    for (int i = tid; i < 32 * 256; i += 256) {
        int row = i >> 8, col = i & 255;
        fbuf[aswz(row, col)] = f2bf(out[(size_t)(c0b + row) * 256 + col]);
    }
    if (tid < 32) cbuf[tid] = log1pf(count[c0b + tid]);
    __syncthreads();

    // ---- o1: g1 = gelu(feat @ o1_w^T + cnt*w256 + b) (kh-split, dbuf) ----
    {
        auto gbase = [&](int g) {
            int nt = g >> 1, kh = g & 1;
            return wb + O1_OFF + ((size_t)(wid * 8 + nt) * 8 + kh * 4) * 512 + lane * 8;
        };
        short8 a0[8], a1[8];
        #pragma unroll
        for (int kt = 0; kt < 8; kt++) {
            a0[kt] = *reinterpret_cast<const short8*>(&fbuf[aswz(cc,      kt * 32 + cq * 8)]);
            a1[kt] = *reinterpret_cast<const short8*>(&fbuf[aswz(16 + cc, kt * 32 + cq * 8)]);
        }
        short8 bb[2][4];
        load_bgrp<4>(bb[0], gbase(0));
        f32x4 c0, c1;
        #pragma unroll
        for (int nt = 0; nt < 8; nt++) {
            #pragma unroll
            for (int kh = 0; kh < 2; kh++) {
                int g = nt * 2 + kh;
                if (g + 1 < 16) load_bgrp<4>(bb[(g + 1) & 1], gbase(g + 1));
                if (kh == 0) {
                    float b = o1_b[wid * 128 + nt * 16 + cc];
                    c0 = (f32x4){b, b, b, b};
                    c1 = (f32x4){b, b, b, b};
                }
                __builtin_amdgcn_s_setprio(1);
                #pragma unroll
                for (int kt = 0; kt < 4; kt++) {
                    c0 = __builtin_amdgcn_mfma_f32_16x16x32_bf16(a0[kh * 4 + kt], bb[g & 1][kt], c0, 0, 0, 0);
                    c1 = __builtin_amdgcn_mfma_f32_16x16x32_bf16(a1[kh * 4 + kt], bb[g & 1][kt], c1, 0, 0, 0);
                }
                __builtin_amdgcn_s_setprio(0);
            }
            int col  = wid * 128 + nt * 16 + cc;
            float wc = w256[col];
            #pragma unroll
            for (int r = 0; r < 4; r++) {
                int r0 = cq * 4 + r, r1 = 16 + cq * 4 + r;
                gbuf[qswz(r0, col)] = f2bf(gelu_f(c0[r] + cbuf[r0] * wc));
                gbuf[qswz(r1, col)] = f2bf(gelu_f(c1[r] + cbuf[r1] * wc));
            }
        }
    }
    __syncthreads();

    // ---- o2: out = g1 @ o2_w^T + b (K=512, kh-outer quarters) ----
    {
        f32x4 c[4][2];
        #pragma unroll
        for (int nt = 0; nt < 4; nt++) {
            float b = o2_b[wid * 64 + nt * 16 + cc];
            c[nt][0] = (f32x4){b, b, b, b};
            c[nt][1] = (f32x4){b, b, b, b};
        }
        auto gbase = [&](int g) {
            int half = g >> 3, kh = (g >> 2) & 1, nt = g & 3;
            return wb + O2_OFF + ((size_t)(wid * 4 + nt) * 16 + half * 8 + kh * 4) * 512 + lane * 8;
        };
        short8 bb[2][4];
        load_bgrp<4>(bb[0], gbase(0));
        #pragma unroll
        for (int half = 0; half < 2; half++) {
            #pragma unroll
            for (int kh = 0; kh < 2; kh++) {
                short8 a0q[4], a1q[4];
                #pragma unroll
                for (int kt = 0; kt < 4; kt++) {
                    int scol = half * 256 + kh * 128 + kt * 32 + cq * 8;
                    a0q[kt] = *reinterpret_cast<const short8*>(&gbuf[qswz(cc,      scol)]);
                    a1q[kt] = *reinterpret_cast<const short8*>(&gbuf[qswz(16 + cc, scol)]);
                }
                #pragma unroll
                for (int nt = 0; nt < 4; nt++) {
                    int g = half * 8 + kh * 4 + nt;
                    if (g + 1 < 16) load_bgrp<4>(bb[(g + 1) & 1], gbase(g + 1));
                    __builtin_amdgcn_s_setprio(1);
                    #pragma unroll
                    for (int kt = 0; kt < 4; kt++) {
                        c[nt][0] = __builtin_amdgcn_mfma_f32_16x16x32_bf16(a0q[kt], bb[g & 1][kt], c[nt][0], 0, 0, 0);
                        c[nt][1] = __builtin_amdgcn_mfma_f32_16x16x32_bf16(a1q[kt], bb[g & 1][kt], c[nt][1], 0, 0, 0);
                    }
                    __builtin_amdgcn_s_setprio(0);
                }
            }
        }
        #pragma unroll
        for (int nt = 0; nt < 4; nt++) {
            int col = wid * 64 + nt * 16 + cc;
            #pragma unroll
            for (int r = 0; r < 4; r++) {
                out[(size_t)(c0b + cq * 4 + r) * 256 + col]      = c[nt][0][r];
                out[(size_t)(c0b + 16 + cq * 4 + r) * 256 + col] = c[nt][1][r];
            }
        }
    }
}

extern "C" void kernel_launch(void* const* d_in, const int* in_sizes, int n_in,
                              void* d_out, int out_size, void* d_ws, size_t ws_size,
                              hipStream_t stream) {
    const float* v          = (const float*)d_in[0];
    const int*   batch_idx  = (const int*)d_in[1];
    const void*  mask       = d_in[2];
    const float* count      = (const float*)d_in[3];
    const float* pos_embed  = (const float*)d_in[4];
    const float* ln1_w      = (const float*)d_in[5];
    const float* ln1_b      = (const float*)d_in[6];
    const float* in_proj_w  = (const float*)d_in[7];
    const float* in_proj_b  = (const float*)d_in[8];
    const float* out_proj_w = (const float*)d_in[9];
    const float* out_proj_b = (const float*)d_in[10];
    const float* ln2_w      = (const float*)d_in[11];
    const float* ln2_b      = (const float*)d_in[12];
    const float* ff1_w      = (const float*)d_in[13];
    const float* ff1_b      = (const float*)d_in[14];
    const float* ff2_w      = (const float*)d_in[15];
    const float* ff2_b      = (const float*)d_in[16];
    const float* o1_w       = (const float*)d_in[17];
    const float* o1_b       = (const float*)d_in[18];
    const float* o2_w       = (const float*)d_in[19];
    const float* o2_b       = (const float*)d_in[20];
    float* out = (float*)d_out;

    unsigned short* wb = (unsigned short*)d_ws;
    float* w256 = (float*)((char*)d_ws + W256_BYTE_OFF);
    int* flag   = (int*)((char*)d_ws + FLAG_BYTE_OFF);

    conv_weights<<<387, 256, 0, stream>>>(in_proj_w, out_proj_w, ff1_w, ff2_w, o1_w, o2_w, wb, w256);
    detect_mask_fmt<<<1, 256, 0, stream>>>((const unsigned int*)mask, 16384, flag);
    tsa_main<<<NCC / G, 512, 0, stream>>>(v, batch_idx, mask, pos_embed,
                                          ln1_w, ln1_b, in_proj_b, out_proj_b,
                                          ln2_w, ln2_b, ff1_b, ff2_b,
                                          wb, flag, out);
    tsa_head<<<NCC / 32, 256, 0, stream>>>(count, o1_b, o2_b, wb, w256, out);
}

// Round 16
// 560.374 us; speedup vs baseline: 1.4703x; 1.4694x over previous
//
#include <hip/hip_runtime.h>
#include <hip/hip_bf16.h>
#include <math.h>

typedef short short8 __attribute__((ext_vector_type(8)));
typedef short short4v __attribute__((ext_vector_type(4)));
typedef float f32x4 __attribute__((ext_vector_type(4)));

#define NCC  32768
#define G    4

// swizzled-weight region offsets in d_ws (units: unsigned short)
#define G1_OFF 0        // in_proj  768x256
#define G2_OFF 196608   // out_proj 256x256
#define G3_OFF 262144   // ff1      512x256
#define G4_OFF 393216   // ff2      256x512
#define O1_OFF 524288   // o1 (first 256 of K=257) 512x256
#define O2_OFF 655360   // o2       256x512
#define SWZ_SHORTS 786432
#define W256_BYTE_OFF (SWZ_SHORTS * 2)
#define FLAG_BYTE_OFF (W256_BYTE_OFF + 2048)

// padded LDS strides (f32) for pool buffers — break power-of-2 bank aliasing
#define PX2_ST 260
#define PGF_ST 520

// Fast GELU (tanh form via sigmoid): x * sigmoid(2*0.79788456*(x+0.044715 x^3)).
// Inputs here have |x| <~ 3 (0.02-scale weights), approx error < 1e-4 << bf16 rounding.
__device__ __forceinline__ float gelu_f(float x) {
    float u  = 1.5957691216057308f * (x + 0.044715f * x * x * x); // 2*sqrt(2/pi)*(...)
    float e  = __expf(-u);
    return x / (1.0f + e);
}
__device__ __forceinline__ unsigned short f2bf(float f) {
    __hip_bfloat16 h = __float2bfloat16(f);
    return *reinterpret_cast<unsigned short*>(&h);
}
// XOR-swizzled index (shorts) for 32x256 A-layout buffer
__device__ __forceinline__ int aswz(int row, int scol) {
    return row * 256 + (scol ^ ((row & 7) << 3));
}
// XOR-swizzled index (shorts) for 32x512 buffer
__device__ __forceinline__ int qswz(int row, int scol) {
    return row * 512 + (scol ^ ((row & 7) << 3));
}
// Vt swizzle: Vt[d][j], d<256, j<32
__device__ __forceinline__ int vtswz(int d, int j) {
    return d * 32 + (j ^ ((d & 7) << 2));
}

template<int KTS>
__device__ __forceinline__ void load_bgrp(short8 (&b)[KTS], const unsigned short* __restrict__ base) {
    #pragma unroll
    for (int kt = 0; kt < KTS; kt++)
        b[kt] = *reinterpret_cast<const short8*>(base + (size_t)kt * 512);
}

// ---- one-time weight swizzle into MFMA B-fragment order ----
__global__ void conv_weights(const float* __restrict__ w1, const float* __restrict__ w2,
                             const float* __restrict__ w3, const float* __restrict__ w4,
                             const float* __restrict__ o1, const float* __restrict__ o2,
                             unsigned short* __restrict__ dst, float* __restrict__ w256) {
    int i = blockIdx.x * 256 + threadIdx.x;
    if (i < 98304) {
        const float* src; int kts, sk, base;
        if (i < 24576)      { src = w1; kts = 8;  sk = 256; base = 0; }
        else if (i < 32768) { src = w2; kts = 8;  sk = 256; base = 24576; }
        else if (i < 49152) { src = w3; kts = 8;  sk = 256; base = 32768; }
        else if (i < 65536) { src = w4; kts = 16; sk = 512; base = 49152; }
        else if (i < 81920) { src = o1; kts = 8;  sk = 257; base = 65536; }
        else                { src = o2; kts = 16; sk = 512; base = 81920; }
        int li   = i - base;
        int lane = li & 63;
        int fi   = li >> 6;
        int kt   = fi % kts;
        int nt   = fi / kts;
        int col  = nt * 16 + (lane & 15);
        int k    = kt * 32 + (lane >> 4) * 8;
        const float* s = src + (size_t)col * sk + k;
        unsigned short* d = dst + (size_t)i * 8;
        #pragma unroll
        for (int e = 0; e < 8; e++) d[e] = f2bf(s[e]);
    } else if (i < 98816) {
        int c = i - 98304;
        w256[c] = o1[(size_t)c * 257 + 256];
    }
}

// ---- mask storage format detect: 0=int32, 1=byte, 2=float32 ----
__global__ void detect_mask_fmt(const unsigned int* __restrict__ mw, int nwords, int* __restrict__ flag) {
    __shared__ int s_bad_int, s_bad_float;
    if (threadIdx.x == 0) { s_bad_int = 0; s_bad_float = 0; }
    __syncthreads();
    int bad_int = 0, bad_float = 0;
    for (int i = threadIdx.x; i < nwords; i += blockDim.x) {
        unsigned int w = mw[i];
        if (w > 1u) bad_int = 1;
        if (w != 0u && w != 0x3F800000u) bad_float = 1;
    }
    if (bad_int)   atomicOr(&s_bad_int, 1);
    if (bad_float) atomicOr(&s_bad_float, 1);
    __syncthreads();
    if (threadIdx.x == 0)
        *flag = (!s_bad_int) ? 0 : ((!s_bad_float) ? 2 : 1);
}

// ===================== main transformer kernel =====================
// Live set <= ~116 regs (proven R10/R12): 2 waves/SIMD, zero spill.
__global__ __launch_bounds__(256, 2)
void tsa_main(const float* __restrict__ v,
              const int* __restrict__ batch_idx,
              const void* __restrict__ mask,
              const float* __restrict__ pos_embed,
              const float* __restrict__ ln1_w, const float* __restrict__ ln1_b,
              const float* __restrict__ in_proj_b,
              const float* __restrict__ out_proj_b,
              const float* __restrict__ ln2_w, const float* __restrict__ ln2_b,
              const float* __restrict__ ff1_b, const float* __restrict__ ff2_b,
              const unsigned short* __restrict__ wb,
              const int* __restrict__ mask_flag,
              float* __restrict__ out)
{
    __shared__ unsigned short qkbuf[32 * 512];      // lnred | Q|K -> ao | px2 | pgff
    __shared__ unsigned short abuf[32 * 256];       // LN1(swz) -> Vt(swz) -> LN2(swz)
    __shared__ unsigned short attw_s[2][4][16][16]; // P (bf16)
    __shared__ int s_idx[G][8];
    __shared__ int s_m[G];
    __shared__ int s_bi[G];

    float* lnred = reinterpret_cast<float*>(qkbuf);           // bytes 0..2048
    float* px2   = reinterpret_cast<float*>(qkbuf + 2048);    // bytes 4096..8256
    float* pgff  = reinterpret_cast<float*>(qkbuf + 8192);    // bytes 16384..24704

    const int tid  = threadIdx.x;
    const int lane = tid & 63;
    const int wid  = tid >> 6;
    const int cq   = lane >> 4;
    const int cc   = lane & 15;
    const int cg0  = blockIdx.x * G;
    const int pair = wid >> 1;

    f32x4 xr[2][4];   // residual: row = mt*16+cq*4+r, col = wid*64+nt*16+cc

    // ---- mask parse (wave w -> chunk w) ----
    {
        int mf = *mask_flag;
        size_t base = (size_t)(cg0 + wid) * 64 + lane;
        int bit;
        if (mf == 0)      bit = ((const int*)mask)[base] != 0;
        else if (mf == 2) bit = ((const float*)mask)[base] != 0.0f;
        else              bit = ((const unsigned char*)mask)[base] != 0;
        unsigned long long bal = __ballot(bit);
        if (lane == 0) {
            int mm = 0; unsigned long long b = bal;
            while (b && mm < 8) { s_idx[wid][mm++] = __ffsll(b) - 1; b &= (b - 1); }
            for (int t = mm; t < 8; t++) s_idx[wid][t] = 0;
            s_m[wid]  = mm;
            s_bi[wid] = batch_idx[cg0 + wid];
        }
    }
    __syncthreads();

    // ---- gather helper: v+pos -> xr regs ----
    auto do_gather = [&]() {
        #pragma unroll
        for (int mt = 0; mt < 2; mt++) {
            int c  = 2 * mt + (cq >> 1);
            int m  = s_m[c];
            int bi = s_bi[c];
            #pragma unroll
            for (int rr = 0; rr < 4; rr++) {
                int rowin = (cq & 1) * 4 + rr;
                int vidx  = s_idx[c][rowin];
                #pragma unroll
                for (int nt = 0; nt < 4; nt++) {
                    int col  = wid * 64 + nt * 16 + cc;
                    float pe = pos_embed[rowin * 256 + col];
                    float val = (rowin < m) ? v[((size_t)bi * 64 + vidx) * 256 + col] : 0.0f;
                    xr[mt][nt][rr] = val + pe;
                }
            }
        }
    };

    // ---- layernorm: xr regs -> abuf (bf16, swizzled) ----
    auto do_ln = [&](const float* __restrict__ lw, const float* __restrict__ lb) {
        float sm[2][4], sq[2][4];
        #pragma unroll
        for (int mt = 0; mt < 2; mt++)
            #pragma unroll
            for (int rr = 0; rr < 4; rr++) {
                float s = 0.f, q = 0.f;
                #pragma unroll
                for (int nt = 0; nt < 4; nt++) {
                    float x = xr[mt][nt][rr];
                    s += x; q += x * x;
                }
                sm[mt][rr] = s; sq[mt][rr] = q;
            }
        #pragma unroll
        for (int off = 1; off < 16; off <<= 1) {
            #pragma unroll
            for (int mt = 0; mt < 2; mt++)
                #pragma unroll
                for (int rr = 0; rr < 4; rr++) {
                    sm[mt][rr] += __shfl_xor(sm[mt][rr], off);
                    sq[mt][rr] += __shfl_xor(sq[mt][rr], off);
                }
        }
        if (cc == 0) {
            #pragma unroll
            for (int mt = 0; mt < 2; mt++)
                #pragma unroll
                for (int rr = 0; rr < 4; rr++) {
                    int row = mt * 16 + cq * 4 + rr;
                    lnred[(wid * 32 + row) * 2 + 0] = sm[mt][rr];
                    lnred[(wid * 32 + row) * 2 + 1] = sq[mt][rr];
                }
        }
        __syncthreads();
        float mu[2][4], rs[2][4];
        #pragma unroll
        for (int mt = 0; mt < 2; mt++)
            #pragma unroll
            for (int rr = 0; rr < 4; rr++) {
                int row = mt * 16 + cq * 4 + rr;
                float S = 0.f, Q = 0.f;
                #pragma unroll
                for (int w = 0; w < 4; w++) {
                    S += lnred[(w * 32 + row) * 2 + 0];
                    Q += lnred[(w * 32 + row) * 2 + 1];
                }
                float m_ = S * (1.0f / 256.0f);
                mu[mt][rr] = m_;
                rs[mt][rr] = rsqrtf(Q * (1.0f / 256.0f) - m_ * m_ + 1e-5f);
            }
        #pragma unroll
        for (int nt = 0; nt < 4; nt++) {
            int col = wid * 64 + nt * 16 + cc;
            float w_ = lw[col], b_ = lb[col];
            #pragma unroll
            for (int mt = 0; mt < 2; mt++)
                #pragma unroll
                for (int rr = 0; rr < 4; rr++) {
                    int row = mt * 16 + cq * 4 + rr;
                    abuf[aswz(row, col)] = f2bf((xr[mt][nt][rr] - mu[mt][rr]) * rs[mt][rr] * w_ + b_);
                }
        }
        __syncthreads();
    };

    auto load_a_abuf = [&](short8 (&a0)[8], short8 (&a1)[8]) {
        #pragma unroll
        for (int kt = 0; kt < 8; kt++) {
            a0[kt] = *reinterpret_cast<const short8*>(&abuf[aswz(cc,      kt * 32 + cq * 8)]);
            a1[kt] = *reinterpret_cast<const short8*>(&abuf[aswz(16 + cc, kt * 32 + cq * 8)]);
        }
    };

    // ---- gather #1 + LN1 (xr dead afterwards) ----
    do_gather();
    do_ln(ln1_w, ln1_b);

    // ---- GEMM1 (merged QKV, NT=12, 4-kt B groups, dbuf) ----
    {
        short8 a0[8], a1[8];
        load_a_abuf(a0, a1);
        __syncthreads();   // a-frags loaded before Vt overwrites abuf

        auto gbase = [&](int g) {
            int nt = g >> 1, kh = g & 1;
            int gnt = (nt < 8) ? (wid * 8 + nt) : (32 + wid * 4 + (nt - 8));
            return wb + G1_OFF + ((size_t)gnt * 8 + kh * 4) * 512 + lane * 8;
        };
        short8 bb[2][4];
        load_bgrp<4>(bb[0], gbase(0));
        f32x4 c0, c1;
        #pragma unroll
        for (int nt = 0; nt < 12; nt++) {
            #pragma unroll
            for (int kh = 0; kh < 2; kh++) {
                int g = nt * 2 + kh;
                if (g + 1 < 24) load_bgrp<4>(bb[(g + 1) & 1], gbase(g + 1));
                if (kh == 0) {
                    float b = (nt < 8) ? in_proj_b[wid * 128 + nt * 16 + cc]
                                       : in_proj_b[512 + wid * 64 + (nt - 8) * 16 + cc];
                    c0 = (f32x4){b, b, b, b};
                    c1 = (f32x4){b, b, b, b};
                }
                __builtin_amdgcn_s_setprio(1);
                #pragma unroll
                for (int kt = 0; kt < 4; kt++) {
                    c0 = __builtin_amdgcn_mfma_f32_16x16x32_bf16(a0[kh * 4 + kt], bb[g & 1][kt], c0, 0, 0, 0);
                    c1 = __builtin_amdgcn_mfma_f32_16x16x32_bf16(a1[kh * 4 + kt], bb[g & 1][kt], c1, 0, 0, 0);
                }
                __builtin_amdgcn_s_setprio(0);
            }
            if (nt < 8) {
                int col = wid * 128 + nt * 16 + cc;
                #pragma unroll
                for (int r = 0; r < 4; r++) {
                    qkbuf[qswz(cq * 4 + r, col)]      = f2bf(c0[r]);
                    qkbuf[qswz(16 + cq * 4 + r, col)] = f2bf(c1[r]);
                }
            } else {
                int d = wid * 64 + (nt - 8) * 16 + cc;
                short4v p0, p1;
                #pragma unroll
                for (int r = 0; r < 4; r++) { p0[r] = (short)f2bf(c0[r]); p1[r] = (short)f2bf(c1[r]); }
                *reinterpret_cast<short4v*>(&abuf[vtswz(d, cq * 4)])      = p0;
                *reinterpret_cast<short4v*>(&abuf[vtswz(d, 16 + cq * 4)]) = p1;
            }
        }
    }
    __syncthreads();

    // ---- re-gather residual (overlaps attention below) ----
    do_gather();

    // ---- attention scores (MFMA) + softmax -> P ----
    {
        #pragma unroll
        for (int hj = 0; hj < 2; hj++) {
            int h = (wid & 1) * 2 + hj;
            f32x4 c = {0.f, 0.f, 0.f, 0.f};
            #pragma unroll
            for (int kt = 0; kt < 2; kt++) {
                short8 qa = *reinterpret_cast<const short8*>(&qkbuf[qswz(pair * 16 + cc, h * 64 + cq * 8 + kt * 32)]);
                short8 kb = *reinterpret_cast<const short8*>(&qkbuf[qswz(pair * 16 + cc, 256 + h * 64 + cq * 8 + kt * 32)]);
                c = __builtin_amdgcn_mfma_f32_16x16x32_bf16(qa, kb, c, 0, 0, 0);
            }
            int jhalf = cc >> 3, jloc = cc & 7;
            #pragma unroll
            for (int r = 0; r < 4; r++) {
                int q = cq * 4 + r;
                int qhalf = q >> 3;
                int m = s_m[pair * 2 + qhalf];
                bool valid = (jhalf == qhalf) && (jloc < m);
                float s = valid ? c[r] * 0.125f : -1e30f;
                float mx = s;
                mx = fmaxf(mx, __shfl_xor(mx, 1));
                mx = fmaxf(mx, __shfl_xor(mx, 2));
                mx = fmaxf(mx, __shfl_xor(mx, 4));
                float e = valid ? __expf(s - mx) : 0.f;
                float se = e;
                se += __shfl_xor(se, 1);
                se += __shfl_xor(se, 2);
                se += __shfl_xor(se, 4);
                attw_s[pair][h][q][cc] = f2bf((se > 0.f) ? e / se : 0.f);
            }
        }
    }
    __syncthreads();

    // ---- PV (MFMA, K=32 zero-padded) -> ao (swizzled into qkbuf) ----
    {
        int jbg = pair * 16 + (cq & 1) * 8;
        #pragma unroll
        for (int hj = 0; hj < 2; hj++) {
            int h = (wid & 1) * 2 + hj;
            short8 pa;
            if (cq < 2) pa = *reinterpret_cast<const short8*>(&attw_s[pair][h][cc][cq * 8]);
            else        pa = (short8)((short)0);
            #pragma unroll
            for (int t = 0; t < 4; t++) {
                int d = h * 64 + t * 16 + cc;
                short4v lo = *reinterpret_cast<const short4v*>(&abuf[vtswz(d, jbg)]);
                short4v hi = *reinterpret_cast<const short4v*>(&abuf[vtswz(d, jbg + 4)]);
                union { short8 vv; short4v half2[2]; } u;
                u.half2[0] = lo; u.half2[1] = hi;
                f32x4 c = {0.f, 0.f, 0.f, 0.f};
                c = __builtin_amdgcn_mfma_f32_16x16x32_bf16(pa, u.vv, c, 0, 0, 0);
                #pragma unroll
                for (int r = 0; r < 4; r++)
                    qkbuf[qswz(pair * 16 + cq * 4 + r, d)] = f2bf(c[r]);
            }
        }
    }
    __syncthreads();

    // ---- GEMM2: xr += ao @ W2^T + b2 (kh-outer: a-half 32 regs) ----
    {
        #pragma unroll
        for (int nt = 0; nt < 4; nt++) {
            float b = out_proj_b[wid * 64 + nt * 16 + cc];
            #pragma unroll
            for (int r = 0; r < 4; r++) { xr[0][nt][r] += b; xr[1][nt][r] += b; }
        }
        auto gbase = [&](int g) {
            int kh = g >> 2, nt = g & 3;
            return wb + G2_OFF + ((size_t)(wid * 4 + nt) * 8 + kh * 4) * 512 + lane * 8;
        };
        short8 bb[2][4];
        load_bgrp<4>(bb[0], gbase(0));
        #pragma unroll
        for (int kh = 0; kh < 2; kh++) {
            short8 a0h[4], a1h[4];
            #pragma unroll
            for (int kt = 0; kt < 4; kt++) {
                a0h[kt] = *reinterpret_cast<const short8*>(&qkbuf[qswz(cc,      kh * 128 + kt * 32 + cq * 8)]);
                a1h[kt] = *reinterpret_cast<const short8*>(&qkbuf[qswz(16 + cc, kh * 128 + kt * 32 + cq * 8)]);
            }
            #pragma unroll
            for (int nt = 0; nt < 4; nt++) {
                int g = kh * 4 + nt;
                if (g + 1 < 8) load_bgrp<4>(bb[(g + 1) & 1], gbase(g + 1));
                __builtin_amdgcn_s_setprio(1);
                #pragma unroll
                for (int kt = 0; kt < 4; kt++) {
                    xr[0][nt] = __builtin_amdgcn_mfma_f32_16x16x32_bf16(a0h[kt], bb[g & 1][kt], xr[0][nt], 0, 0, 0);
                    xr[1][nt] = __builtin_amdgcn_mfma_f32_16x16x32_bf16(a1h[kt], bb[g & 1][kt], xr[1][nt], 0, 0, 0);
                }
                __builtin_amdgcn_s_setprio(0);
            }
        }
    }
    __syncthreads();

    // ---- pool x2 -> px2 LDS (padded stride) ----
    #pragma unroll
    for (int mt = 0; mt < 2; mt++) {
        int c = 2 * mt + (cq >> 1);
        int m = s_m[c];
        #pragma unroll
        for (int nt = 0; nt < 4; nt++) {
            float p = 0.f;
            #pragma unroll
            for (int rr = 0; rr < 4; rr++)
                if ((cq & 1) * 4 + rr < m) p += xr[mt][nt][rr];
            p += __shfl_xor(p, 16);
            if ((cq & 1) == 0) {
                int col = wid * 64 + nt * 16 + cc;
                px2[c * PX2_ST + col] = p;
            }
        }
    }

    // ---- LN2 ----
    do_ln(ln2_w, ln2_b);

    // ---- GEMM3: gelu(h2 @ W3^T + b3) pooled on the fly -> pgff (gff never stored) ----
    {
        short8 a0[8], a1[8];
        load_a_abuf(a0, a1);
        auto gbase = [&](int g) {
            int nt = g >> 1, kh = g & 1;
            return wb + G3_OFF + ((size_t)(wid * 8 + nt) * 8 + kh * 4) * 512 + lane * 8;
        };
        short8 bb[2][4];
        load_bgrp<4>(bb[0], gbase(0));
        f32x4 c0, c1;
        #pragma unroll
        for (int nt = 0; nt < 8; nt++) {
            #pragma unroll
            for (int kh = 0; kh < 2; kh++) {
                int g = nt * 2 + kh;
                if (g + 1 < 16) load_bgrp<4>(bb[(g + 1) & 1], gbase(g + 1));
                if (kh == 0) {
                    float b = ff1_b[wid * 128 + nt * 16 + cc];
                    c0 = (f32x4){b, b, b, b};
                    c1 = (f32x4){b, b, b, b};
                }
                __builtin_amdgcn_s_setprio(1);
                #pragma unroll
                for (int kt = 0; kt < 4; kt++) {
                    c0 = __builtin_amdgcn_mfma_f32_16x16x32_bf16(a0[kh * 4 + kt], bb[g & 1][kt], c0, 0, 0, 0);
                    c1 = __builtin_amdgcn_mfma_f32_16x16x32_bf16(a1[kh * 4 + kt], bb[g & 1][kt], c1, 0, 0, 0);
                }
                __builtin_amdgcn_s_setprio(0);
            }
            // epilogue: gelu + masked row-sum per chunk -> pgff
            int col = wid * 128 + nt * 16 + cc;
            float s0 = 0.f, s1 = 0.f;
            int m0 = s_m[cq >> 1];
            int m1 = s_m[2 + (cq >> 1)];
            #pragma unroll
            for (int r = 0; r < 4; r++) {
                float g0 = gelu_f(c0[r]);
                float g1 = gelu_f(c1[r]);
                if ((cq & 1) * 4 + r < m0) s0 += g0;
                if ((cq & 1) * 4 + r < m1) s1 += g1;
            }
            s0 += __shfl_xor(s0, 16);
            s1 += __shfl_xor(s1, 16);
            if ((cq & 1) == 0) {
                pgff[(cq >> 1) * PGF_ST + col]       = s0;
                pgff[(2 + (cq >> 1)) * PGF_ST + col] = s1;
            }
        }
    }
    __syncthreads();

    // ---- GEMV4 (4-row MFMA): pooled = (px2 + pgff @ W4^T)/m + b4 ----
    {
        auto gbase = [&](int g) {
            int kh = g >> 2, nt = g & 3;
            return wb + G4_OFF + ((size_t)(wid * 4 + nt) * 16 + kh * 4) * 512 + lane * 8;
        };
        short8 bb[2][4];
        load_bgrp<4>(bb[0], gbase(0));
        f32x4 acc[4];
        #pragma unroll
        for (int nt = 0; nt < 4; nt++) acc[nt] = (f32x4){0.f, 0.f, 0.f, 0.f};
        #pragma unroll
        for (int kh = 0; kh < 4; kh++) {
            short8 af[4];
            #pragma unroll
            for (int kt = 0; kt < 4; kt++) {
                short8 t = (short8)((short)0);
                if (cc < 4) {
                    const float4* s4 = reinterpret_cast<const float4*>(&pgff[cc * PGF_ST + (kh * 4 + kt) * 32 + cq * 8]);
                    float4 x0 = s4[0];
                    float4 x1 = s4[1];
                    t[0] = (short)f2bf(x0.x); t[1] = (short)f2bf(x0.y);
                    t[2] = (short)f2bf(x0.z); t[3] = (short)f2bf(x0.w);
                    t[4] = (short)f2bf(x1.x); t[5] = (short)f2bf(x1.y);
                    t[6] = (short)f2bf(x1.z); t[7] = (short)f2bf(x1.w);
                }
                af[kt] = t;
            }
            #pragma unroll
            for (int nt = 0; nt < 4; nt++) {
                int g = kh * 4 + nt;
                if (g + 1 < 16) load_bgrp<4>(bb[(g + 1) & 1], gbase(g + 1));
                __builtin_amdgcn_s_setprio(1);
                #pragma unroll
                for (int kt = 0; kt < 4; kt++)
                    acc[nt] = __builtin_amdgcn_mfma_f32_16x16x32_bf16(af[kt], bb[g & 1][kt], acc[nt], 0, 0, 0);
                __builtin_amdgcn_s_setprio(0);
            }
        }
        if (cq == 0) {
            #pragma unroll
            for (int nt = 0; nt < 4; nt++) {
                int col = wid * 64 + nt * 16 + cc;
                float b4 = ff2_b[col];
                #pragma unroll
                for (int r = 0; r < 4; r++) {
                    int m = s_m[r];
                    float val = 0.f;
                    if (m > 0) val = (px2[r * PX2_ST + col] + acc[nt][r]) / (float)m + b4;
                    out[(size_t)(cg0 + r) * 256 + col] = val;
                }
            }
        }
    }
}

// ===================== head kernel (32 chunks/block, MFMA) =====================
__global__ __launch_bounds__(256, 2)
void tsa_head(const float* __restrict__ count,
              const float* __restrict__ o1_b, const float* __restrict__ o2_b,
              const unsigned short* __restrict__ wb, const float* __restrict__ w256,
              float* __restrict__ out)
{
    __shared__ unsigned short fbuf[32 * 256];
    __shared__ unsigned short gbuf[32 * 512];
    __shared__ float cbuf[32];

    const int tid  = threadIdx.x;
    const int lane = tid & 63;
    const int wid  = tid >> 6;
    const int cq   = lane >> 4;
    const int cc   = lane & 15;
    const int c0b  = blockIdx.x * 32;

    for (int i = tid; i < 32 * 256; i += 256) {
        int row = i >> 8, col = i & 255;
        fbuf[aswz(row, col)] = f2bf(out[(size_t)(c0b + row) * 256 + col]);
    }
    if (tid < 32) cbuf[tid] = log1pf(count[c0b + tid]);
    __syncthreads();

    // ---- o1: g1 = gelu(feat @ o1_w^T + cnt*w256 + b) (kh-split, dbuf) ----
    {
        auto gbase = [&](int g) {
            int nt = g >> 1, kh = g & 1;
            return wb + O1_OFF + ((size_t)(wid * 8 + nt) * 8 + kh * 4) * 512 + lane * 8;
        };
        short8 a0[8], a1[8];
        #pragma unroll
        for (int kt = 0; kt < 8; kt++) {
            a0[kt] = *reinterpret_cast<const short8*>(&fbuf[aswz(cc,      kt * 32 + cq * 8)]);
            a1[kt] = *reinterpret_cast<const short8*>(&fbuf[aswz(16 + cc, kt * 32 + cq * 8)]);
        }
        short8 bb[2][4];
        load_bgrp<4>(bb[0], gbase(0));
        f32x4 c0, c1;
        #pragma unroll
        for (int nt = 0; nt < 8; nt++) {
            #pragma unroll
            for (int kh = 0; kh < 2; kh++) {
                int g = nt * 2 + kh;
                if (g + 1 < 16) load_bgrp<4>(bb[(g + 1) & 1], gbase(g + 1));
                if (kh == 0) {
                    float b = o1_b[wid * 128 + nt * 16 + cc];
                    c0 = (f32x4){b, b, b, b};
                    c1 = (f32x4){b, b, b, b};
                }
                __builtin_amdgcn_s_setprio(1);
                #pragma unroll
                for (int kt = 0; kt < 4; kt++) {
                    c0 = __builtin_amdgcn_mfma_f32_16x16x32_bf16(a0[kh * 4 + kt], bb[g & 1][kt], c0, 0, 0, 0);
                    c1 = __builtin_amdgcn_mfma_f32_16x16x32_bf16(a1[kh * 4 + kt], bb[g & 1][kt], c1, 0, 0, 0);
                }
                __builtin_amdgcn_s_setprio(0);
            }
            int col  = wid * 128 + nt * 16 + cc;
            float wc = w256[col];
            #pragma unroll
            for (int r = 0; r < 4; r++) {
                int r0 = cq * 4 + r, r1 = 16 + cq * 4 + r;
                gbuf[qswz(r0, col)] = f2bf(gelu_f(c0[r] + cbuf[r0] * wc));
                gbuf[qswz(r1, col)] = f2bf(gelu_f(c1[r] + cbuf[r1] * wc));
            }
        }
    }
    __syncthreads();

    // ---- o2: out = g1 @ o2_w^T + b (K=512, kh-outer quarters) ----
    {
        f32x4 c[4][2];
        #pragma unroll
        for (int nt = 0; nt < 4; nt++) {
            float b = o2_b[wid * 64 + nt * 16 + cc];
            c[nt][0] = (f32x4){b, b, b, b};
            c[nt][1] = (f32x4){b, b, b, b};
        }
        auto gbase = [&](int g) {
            int half = g >> 3, kh = (g >> 2) & 1, nt = g & 3;
            return wb + O2_OFF + ((size_t)(wid * 4 + nt) * 16 + half * 8 + kh * 4) * 512 + lane * 8;
        };
        short8 bb[2][4];
        load_bgrp<4>(bb[0], gbase(0));
        #pragma unroll
        for (int half = 0; half < 2; half++) {
            #pragma unroll
            for (int kh = 0; kh < 2; kh++) {
                short8 a0q[4], a1q[4];
                #pragma unroll
                for (int kt = 0; kt < 4; kt++) {
                    int scol = half * 256 + kh * 128 + kt * 32 + cq * 8;
                    a0q[kt] = *reinterpret_cast<const short8*>(&gbuf[qswz(cc,      scol)]);
                    a1q[kt] = *reinterpret_cast<const short8*>(&gbuf[qswz(16 + cc, scol)]);
                }
                #pragma unroll
                for (int nt = 0; nt < 4; nt++) {
                    int g = half * 8 + kh * 4 + nt;
                    if (g + 1 < 16) load_bgrp<4>(bb[(g + 1) & 1], gbase(g + 1));
                    __builtin_amdgcn_s_setprio(1);
                    #pragma unroll
                    for (int kt = 0; kt < 4; kt++) {
                        c[nt][0] = __builtin_amdgcn_mfma_f32_16x16x32_bf16(a0q[kt], bb[g & 1][kt], c[nt][0], 0, 0, 0);
                        c[nt][1] = __builtin_amdgcn_mfma_f32_16x16x32_bf16(a1q[kt], bb[g & 1][kt], c[nt][1], 0, 0, 0);
                    }
                    __builtin_amdgcn_s_setprio(0);
                }
            }
        }
        #pragma unroll
        for (int nt = 0; nt < 4; nt++) {
            int col = wid * 64 + nt * 16 + cc;
            #pragma unroll
            for (int r = 0; r < 4; r++) {
                out[(size_t)(c0b + cq * 4 + r) * 256 + col]      = c[nt][0][r];
                out[(size_t)(c0b + 16 + cq * 4 + r) * 256 + col] = c[nt][1][r];
            }
        }
    }
}

extern "C" void kernel_launch(void* const* d_in, const int* in_sizes, int n_in,
                              void* d_out, int out_size, void* d_ws, size_t ws_size,
                              hipStream_t stream) {
    const float* v          = (const float*)d_in[0];
    const int*   batch_idx  = (const int*)d_in[1];
    const void*  mask       = d_in[2];
    const float* count      = (const float*)d_in[3];
    const float* pos_embed  = (const float*)d_in[4];
    const float* ln1_w      = (const float*)d_in[5];
    const float* ln1_b      = (const float*)d_in[6];
    const float* in_proj_w  = (const float*)d_in[7];
    const float* in_proj_b  = (const float*)d_in[8];
    const float* out_proj_w = (const float*)d_in[9];
    const float* out_proj_b = (const float*)d_in[10];
    const float* ln2_w      = (const float*)d_in[11];
    const float* ln2_b      = (const float*)d_in[12];
    const float* ff1_w      = (const float*)d_in[13];
    const float* ff1_b      = (const float*)d_in[14];
    const float* ff2_w      = (const float*)d_in[15];
    const float* ff2_b      = (const float*)d_in[16];
    const float* o1_w       = (const float*)d_in[17];
    const float* o1_b       = (const float*)d_in[18];
    const float* o2_w       = (const float*)d_in[19];
    const float* o2_b       = (const float*)d_in[20];
    float* out = (float*)d_out;

    unsigned short* wb = (unsigned short*)d_ws;
    float* w256 = (float*)((char*)d_ws + W256_BYTE_OFF);
    int* flag   = (int*)((char*)d_ws + FLAG_BYTE_OFF);

    conv_weights<<<387, 256, 0, stream>>>(in_proj_w, out_proj_w, ff1_w, ff2_w, o1_w, o2_w, wb, w256);
    detect_mask_fmt<<<1, 256, 0, stream>>>((const unsigned int*)mask, 16384, flag);
    tsa_main<<<NCC / G, 256, 0, stream>>>(v, batch_idx, mask, pos_embed,
                                          ln1_w, ln1_b, in_proj_b, out_proj_b,
                                          ln2_w, ln2_b, ff1_b, ff2_b,
                                          wb, flag, out);
    tsa_head<<<NCC / 32, 256, 0, stream>>>(count, o1_b, o2_b, wb, w256, out);
}